// Round 13
// baseline (258.693 us; speedup 1.0000x reference)
//
#include <hip/hip_runtime.h>
#include <hip/hip_bf16.h>
#include <math.h>

// Problem constants (DecoderBlock: B=2, S=2048, D=512, H=8, DFF=2048)
#define BB 2
#define SS 2048
#define DD 512
#define HH 8
#define DH 64
#define DFF 2048
#define MM (BB*SS)          // 4096 rows
#define EPS 1e-5f
#define PSEG ((size_t)MM * DD)

typedef __attribute__((ext_vector_type(8))) short bf16x8;
typedef __attribute__((ext_vector_type(4))) float f32x4;

// Async global->LDS, 16B per lane. LDS dest is wave-uniform base + lane*16;
// the GLOBAL address may be per-lane (gather) — only the LDS side is linear.
#define GL2LDS(g, l)                                                        \
    __builtin_amdgcn_global_load_lds(                                       \
        (const __attribute__((address_space(1))) void*)(unsigned long long)(g), \
        (__attribute__((address_space(3))) void*)(unsigned int)(unsigned long long)(l), \
        16, 0, 0)

// ---------------------------------------------------------------------------
// fp32 -> bf16 conversion for x + 6 weight matrices, one launch.
// ---------------------------------------------------------------------------
struct Cvt7 {
    const float* s[7];
    unsigned short* d[7];
    unsigned off[8];   // prefix offsets in float4 units
};

__global__ __launch_bounds__(256) void cvt_k(Cvt7 a)
{
    unsigned i = blockIdx.x * 256 + threadIdx.x;
    int seg = 0;
    #pragma unroll
    for (int t = 1; t < 7; ++t) seg += (i >= a.off[t]);
    unsigned li = i - a.off[seg];
    float4 v = ((const float4*)a.s[seg])[li];
    union { __hip_bfloat16 h[4]; uint2 u; } t;
    t.h[0] = __float2bfloat16(v.x);
    t.h[1] = __float2bfloat16(v.y);
    t.h[2] = __float2bfloat16(v.z);
    t.h[3] = __float2bfloat16(v.w);
    ((uint2*)a.d[seg])[li] = t.u;
}

// ---------------------------------------------------------------------------
// W-RESIDENT GEMM (round 13). One 64n x 512k W-panel staged into 64 KB LDS
// ONCE (single barrier per block — r12's per-k-iter 2-barrier structure was
// the drain tax), rotation-swizzled per row so ds_read_b128 is conflict-free
// (plain frag-order layout is a 16-way conflict: bank depends on k only).
// 4 waves; wave w computes a 64m x 64n x 512k product with A-fragments
// streamed directly from global (L2-hot). 256 MFMA/wave, 0 barriers in loop.
//   rot(row) = row & 7 (16B chunks): stage lane l <- global chunk (l+rot)&63;
//   read chunk c at LDS pos (c-rot)&63.
// mode 0: raw fp32 partial -> (float*)dst + z*MM*N_   (split-K via gridDim.z)
// mode 1: QKV scatter (type = n0>>9): Q*0.125/K -> [B,H,S,DH], V^T -> [B,H,DH,S]
// mode 3: relu -> bf16 [M,N_]
// ---------------------------------------------------------------------------
__global__ __launch_bounds__(256) void gemm_wres_k(
    const __hip_bfloat16* __restrict__ A, const __hip_bfloat16* __restrict__ W,
    const float* __restrict__ bias, void* __restrict__ dst,
    __hip_bfloat16* __restrict__ qdst, __hip_bfloat16* __restrict__ kdst,
    __hip_bfloat16* __restrict__ vdst,
    const float* __restrict__ bq, const float* __restrict__ bk,
    const float* __restrict__ bv,
    int N_, int Ktot, int mode)
{
    __shared__ __hip_bfloat16 Ws[64 * 512];      // 64 KiB
    const int tid   = threadIdx.x;
    const int w     = tid >> 6;
    const int lane  = tid & 63;
    const int quad  = lane >> 4;
    const int col16 = lane & 15;
    const int n0 = blockIdx.x * 64;
    const int m0 = blockIdx.y * 256;
    const int kbase = blockIdx.z * 512;

    // ---- stage W-panel (rot-swizzled), one barrier ----
    #pragma unroll
    for (int i = 0; i < 16; ++i) {
        const int row = w * 16 + i;
        const int rot = row & 7;
        const int src = ((lane + rot) & 63) * 8;         // element offset
        GL2LDS(W + (size_t)(n0 + row) * Ktot + kbase + src, Ws + row * 512);
    }
    __syncthreads();

    // ---- 64m x 64n x 512k per wave, no barriers ----
    const int mw = m0 + w * 64;
    f32x4 acc[4][4] = {};
    #pragma unroll 2
    for (int ks = 0; ks < 16; ++ks) {
        bf16x8 af[4], wf[4];
        #pragma unroll
        for (int mi = 0; mi < 4; ++mi)
            af[mi] = *(const bf16x8*)(A + (size_t)(mw + mi*16 + col16) * Ktot
                                        + kbase + ks*32 + quad*8);
        #pragma unroll
        for (int nj = 0; nj < 4; ++nj) {
            const int row = nj*16 + col16;
            const int chunk = (ks*4 + quad - (col16 & 7)) & 63;
            wf[nj] = *(const bf16x8*)(Ws + row * 512 + chunk * 8);
        }
        #pragma unroll
        for (int mi = 0; mi < 4; ++mi)
            #pragma unroll
            for (int nj = 0; nj < 4; ++nj)
                acc[mi][nj] = __builtin_amdgcn_mfma_f32_16x16x32_bf16(
                    af[mi], wf[nj], acc[mi][nj], 0, 0, 0);
    }

    // ---- epilogue ----
    if (mode == 0) {
        float* part = (float*)dst + (size_t)blockIdx.z * MM * N_;
        #pragma unroll
        for (int mi = 0; mi < 4; ++mi)
            #pragma unroll
            for (int r = 0; r < 4; ++r) {
                const int m = mw + mi*16 + quad*4 + r;
                #pragma unroll
                for (int nj = 0; nj < 4; ++nj)
                    part[(size_t)m * N_ + n0 + nj*16 + col16] = acc[mi][nj][r];
            }
    } else if (mode == 3) {
        __hip_bfloat16* o = (__hip_bfloat16*)dst;
        #pragma unroll
        for (int mi = 0; mi < 4; ++mi)
            #pragma unroll
            for (int r = 0; r < 4; ++r) {
                const int m = mw + mi*16 + quad*4 + r;
                #pragma unroll
                for (int nj = 0; nj < 4; ++nj) {
                    const int n = n0 + nj*16 + col16;
                    o[(size_t)m * N_ + n] =
                        __float2bfloat16(fmaxf(acc[mi][nj][r] + bias[n], 0.f));
                }
            }
    } else {
        const int z = n0 >> 9;                   // uniform per block
        const float* bi = (z == 0) ? bq : (z == 1) ? bk : bv;
        __hip_bfloat16* o = (z == 0) ? qdst : (z == 1) ? kdst : vdst;
        const float sc = (z == 0) ? 0.125f : 1.0f;
        #pragma unroll
        for (int mi = 0; mi < 4; ++mi)
            #pragma unroll
            for (int r = 0; r < 4; ++r) {
                const int m = mw + mi*16 + quad*4 + r;
                const int b = m >> 11, s = m & (SS - 1);
                #pragma unroll
                for (int nj = 0; nj < 4; ++nj) {
                    const int n  = n0 + nj*16 + col16;
                    const int nn = n & 511;
                    const int hh = nn >> 6, d = nn & (DH - 1);
                    float vv = (acc[mi][nj][r] + bi[nn]) * sc;
                    if (z < 2)
                        o[(((size_t)(b*HH + hh))*SS + s)*DH + d] = __float2bfloat16(vv);
                    else
                        o[(((size_t)(b*HH + hh))*DH + d)*SS + s] = __float2bfloat16(vv);
                }
            }
    }
}

// ---------------------------------------------------------------------------
// MFMA flash attention, causal — r11/r12's 8-wave version (unchanged).
// ---------------------------------------------------------------------------
__global__ __launch_bounds__(512) void attn_mfma_k(
    const __hip_bfloat16* __restrict__ Q,
    const __hip_bfloat16* __restrict__ K,
    const __hip_bfloat16* __restrict__ VT,
    const float* __restrict__ halpha,
    __hip_bfloat16* __restrict__ ctx)
{
    const int w    = threadIdx.x >> 6;   // 0..7
    const int lane = threadIdx.x & 63;
    const int quad = lane >> 4;
    const int col  = lane & 15;
    const int bh   = blockIdx.x;
    const int b    = bh >> 3, h = bh & 7;
    const int qt   = gridDim.y - 1 - blockIdx.y;   // deepest tiles first
    const int q0   = qt * 64;
    const int nchunk = qt + 1;

    const __hip_bfloat16* Qbh = Q  + (size_t)bh * SS * DH;
    const __hip_bfloat16* Kbh = K  + (size_t)bh * SS * DH;
    const __hip_bfloat16* Vbh = VT + (size_t)bh * DH * SS;

    __shared__ float smem[16896];
    __hip_bfloat16* bb     = (__hip_bfloat16*)smem;
    __hip_bfloat16* p_base = bb + (size_t)w * 4096;
    float* lbuf = smem + 16384;

    bf16x8 qf[4][2];
    #pragma unroll
    for (int mi = 0; mi < 4; ++mi) {
        const __hip_bfloat16* qp = Qbh + (size_t)(q0 + mi*16 + col) * DH + quad * 8;
        qf[mi][0] = *(const bf16x8*)(qp);
        qf[mi][1] = *(const bf16x8*)(qp + 32);
    }

    f32x4 acc_o[4][4] = {};
    float lp[4][4] = {};

    for (int c = w; c < nchunk; c += 8) {
        const int k0 = c * 64;
        const bool diag = (c == qt);

        #pragma unroll
        for (int ks = 0; ks < 4; ++ks) {
            const __hip_bfloat16* kp = Kbh + (size_t)(k0 + ks*16 + col) * DH + quad * 8;
            bf16x8 kb0 = *(const bf16x8*)(kp);
            bf16x8 kb1 = *(const bf16x8*)(kp + 32);
            const int keyl = ks*16 + col;
            const int kh = keyl >> 5;
            const int lr = ((keyl >> 3) & 3) * 16;
            const int j  = keyl & 7;
            const int kg = k0 + keyl;
            #pragma unroll
            for (int mi = 0; mi < 4; ++mi) {
                f32x4 s = {};
                s = __builtin_amdgcn_mfma_f32_16x16x32_bf16(qf[mi][0], kb0, s, 0, 0, 0);
                s = __builtin_amdgcn_mfma_f32_16x16x32_bf16(qf[mi][1], kb1, s, 0, 0, 0);
                #pragma unroll
                for (int r = 0; r < 4; ++r) {
                    float p;
                    if (diag) {
                        int qg = q0 + mi*16 + quad*4 + r;
                        p = (kg > qg) ? 0.f : __expf(s[r]);
                    } else {
                        p = __expf(s[r]);
                    }
                    lp[mi][r] += p;
                    p_base[mi*1024 + kh*512 + (lr + quad*4 + r)*8 + j] =
                        __float2bfloat16(p);
                }
            }
        }

        bf16x8 pa[4][2];
        #pragma unroll
        for (int mi = 0; mi < 4; ++mi) {
            pa[mi][0] = *(const bf16x8*)(p_base + mi*1024 + lane*8);
            pa[mi][1] = *(const bf16x8*)(p_base + mi*1024 + 512 + lane*8);
        }
        #pragma unroll
        for (int d = 0; d < 4; ++d) {
            const __hip_bfloat16* vp = Vbh + (size_t)(d*16 + col) * SS + k0 + quad * 8;
            bf16x8 vb0 = *(const bf16x8*)(vp);
            bf16x8 vb1 = *(const bf16x8*)(vp + 32);
            #pragma unroll
            for (int mi = 0; mi < 4; ++mi) {
                acc_o[mi][d] = __builtin_amdgcn_mfma_f32_16x16x32_bf16(pa[mi][0], vb0, acc_o[mi][d], 0, 0, 0);
                acc_o[mi][d] = __builtin_amdgcn_mfma_f32_16x16x32_bf16(pa[mi][1], vb1, acc_o[mi][d], 0, 0, 0);
            }
        }
    }

    #pragma unroll
    for (int mi = 0; mi < 4; ++mi)
        #pragma unroll
        for (int r = 0; r < 4; ++r) {
            float s_ = lp[mi][r];
            #pragma unroll
            for (int o = 1; o < 16; o <<= 1) s_ += __shfl_xor(s_, o);
            lp[mi][r] = s_;
        }

    __syncthreads();
    __hip_bfloat16* obuf = bb + (size_t)w * 4096;
    #pragma unroll
    for (int mi = 0; mi < 4; ++mi)
        #pragma unroll
        for (int d = 0; d < 4; ++d)
            #pragma unroll
            for (int r = 0; r < 4; ++r)
                obuf[(mi*16 + quad*4 + r)*64 + d*16 + col] =
                    __float2bfloat16(acc_o[mi][d][r]);
    if (col == 0) {
        #pragma unroll
        for (int mi = 0; mi < 4; ++mi)
            #pragma unroll
            for (int r = 0; r < 4; ++r)
                lbuf[w*64 + mi*16 + quad*4 + r] = lp[mi][r];
    }
    __syncthreads();

    const float ha = halpha[h];
    #pragma unroll
    for (int rr = 0; rr < 8; ++rr) {
        const int row = w*8 + rr;
        float L = 0.f, val = 0.f;
        #pragma unroll
        for (int p = 0; p < 8; ++p) {
            L   += lbuf[p*64 + row];
            val += __bfloat162float(bb[p*4096 + row*64 + lane]);
        }
        ctx[((size_t)(b*SS + q0 + row))*DD + h*64 + lane] =
            __float2bfloat16(val * ha / L);
    }
}

// ---------------------------------------------------------------------------
// Fused split-K reduce (np partials) + bias + residual + LayerNorm.
// ---------------------------------------------------------------------------
__global__ __launch_bounds__(256) void ln_red_k(
    const float* __restrict__ parts, int np,
    const float* __restrict__ bias, const float* __restrict__ resid,
    const float* __restrict__ g, const float* __restrict__ bta,
    float* __restrict__ out, __hip_bfloat16* __restrict__ outb)
{
    const int row = blockIdx.x;
    const size_t base = (size_t)row * DD;
    const int t = threadIdx.x;
    float v0 = bias[t]       + resid[base + t];
    float v1 = bias[t + 256] + resid[base + t + 256];
    for (int p = 0; p < np; ++p) {
        v0 += parts[p * PSEG + base + t];
        v1 += parts[p * PSEG + base + t + 256];
    }
    __shared__ float red[256];
    red[t] = v0 + v1;
    __syncthreads();
    for (int o = 128; o > 0; o >>= 1) { if (t < o) red[t] += red[t + o]; __syncthreads(); }
    float mu = red[0] * (1.f / DD);
    __syncthreads();
    float d0 = v0 - mu, d1 = v1 - mu;
    red[t] = d0*d0 + d1*d1;
    __syncthreads();
    for (int o = 128; o > 0; o >>= 1) { if (t < o) red[t] += red[t + o]; __syncthreads(); }
    float rstd = rsqrtf(red[0] * (1.f / DD) + EPS);
    float o0 = d0 * rstd * g[t]       + bta[t];
    float o1 = d1 * rstd * g[t + 256] + bta[t + 256];
    out[base + t]       = o0;
    out[base + t + 256] = o1;
    if (outb) {
        outb[base + t]       = __float2bfloat16(o0);
        outb[base + t + 256] = __float2bfloat16(o1);
    }
}

// ---------------------------------------------------------------------------
extern "C" void kernel_launch(void* const* d_in, const int* in_sizes, int n_in,
                              void* d_out, int out_size, void* d_ws, size_t ws_size,
                              hipStream_t stream)
{
    const float* x    = (const float*)d_in[0];
    // d_in[1] = attn_mask (standard causal; handled structurally)
    const float* Wq   = (const float*)d_in[2];
    const float* bq   = (const float*)d_in[3];
    const float* Wk   = (const float*)d_in[4];
    const float* bk   = (const float*)d_in[5];
    const float* Wv   = (const float*)d_in[6];
    const float* bv   = (const float*)d_in[7];
    const float* Wo   = (const float*)d_in[8];
    const float* bo   = (const float*)d_in[9];
    const float* hal  = (const float*)d_in[10];
    const float* ln1g = (const float*)d_in[11];
    const float* ln1b = (const float*)d_in[12];
    const float* W1   = (const float*)d_in[13];
    const float* b1   = (const float*)d_in[14];
    const float* W2   = (const float*)d_in[15];
    const float* b2   = (const float*)d_in[16];
    const float* ln2g = (const float*)d_in[17];
    const float* ln2b = (const float*)d_in[18];
    float* out = (float*)d_out;

    char* ws = (char*)d_ws;
    const size_t MB = 1ull << 20;
    // Lifetime plan (peak 66 MiB):
    //  [0,1.5) Wqkv  [1.5,2) Wob  [2,4) W1b  [4,6) W2b
    //  [6,10)  xb                          (dead after QKV)
    //  [10,14) qb  [14,18) kb  [18,22) vtb (dead after attn)
    //  [22,26) ctxb                        (dead after out-proj)
    //  [26,34) part (out-proj np=1; dead after ln_red1)
    //  [58,66) h fp32                      (live through FFN2 residual)
    //  [22,26) hb bf16 (over dead ctxb; dead after FFN1)
    //  [ 6,22) ff1b bf16 [M,DFF] (over dead xb/qkv)
    //  [26,58) part2 (FFN2 split-K=4, over dead part)
    __hip_bfloat16* Wqkv = (__hip_bfloat16*)(ws);
    __hip_bfloat16* Wob  = (__hip_bfloat16*)(ws + MB + MB/2);
    __hip_bfloat16* W1b  = (__hip_bfloat16*)(ws + 2*MB);
    __hip_bfloat16* W2b  = (__hip_bfloat16*)(ws + 4*MB);
    __hip_bfloat16* xb   = (__hip_bfloat16*)(ws + 6*MB);
    __hip_bfloat16* qb   = (__hip_bfloat16*)(ws + 10*MB);
    __hip_bfloat16* kb   = (__hip_bfloat16*)(ws + 14*MB);
    __hip_bfloat16* vtb  = (__hip_bfloat16*)(ws + 18*MB);
    __hip_bfloat16* ctxb = (__hip_bfloat16*)(ws + 22*MB);
    float* part = (float*)(ws + 26*MB);
    float* h    = (float*)(ws + 58*MB);
    __hip_bfloat16* hb   = (__hip_bfloat16*)(ws + 22*MB);
    __hip_bfloat16* ff1b = (__hip_bfloat16*)(ws + 6*MB);

    dim3 blk(256);

    // fp32 -> bf16: x, Wq, Wk, Wv, Wo, W1, W2 (Wq/Wk/Wv contiguous -> Wqkv)
    Cvt7 ca;
    ca.s[0] = x;  ca.d[0] = (unsigned short*)xb;
    ca.s[1] = Wq; ca.d[1] = (unsigned short*)Wqkv;
    ca.s[2] = Wk; ca.d[2] = (unsigned short*)(Wqkv + 512*512);
    ca.s[3] = Wv; ca.d[3] = (unsigned short*)(Wqkv + 2*512*512);
    ca.s[4] = Wo; ca.d[4] = (unsigned short*)Wob;
    ca.s[5] = W1; ca.d[5] = (unsigned short*)W1b;
    ca.s[6] = W2; ca.d[6] = (unsigned short*)W2b;
    unsigned offs[8] = {0, 524288, 589824, 655360, 720896, 786432, 1048576, 1310720};
    for (int i = 0; i < 8; ++i) ca.off[i] = offs[i];
    cvt_k<<<dim3(5120), blk, 0, stream>>>(ca);

    // QKV: W-resident, grid (1536/64, 4096/256) = (24,16) = 384 blocks
    gemm_wres_k<<<dim3(24, 16), blk, 0, stream>>>(
        xb, Wqkv, nullptr, nullptr, qb, kb, vtb, bq, bk, bv, DD, DD, 1);

    // MFMA flash attention (64q tiles, 8-wave blocks, chunks mod 8)
    attn_mfma_k<<<dim3(BB*HH, SS/64), dim3(512), 0, stream>>>(
        qb, kb, vtb, hal, ctxb);

    // Out-proj: W-resident raw partial, grid (8,16) = 128 blocks
    gemm_wres_k<<<dim3(8, 16), blk, 0, stream>>>(
        ctxb, Wob, nullptr, part, nullptr, nullptr, nullptr,
        nullptr, nullptr, nullptr, DD, DD, 0);
    // LN1 fused reduce: part + bo + x -> h, hb
    ln_red_k<<<dim3(MM), blk, 0, stream>>>(
        part, 1, bo, x, ln1g, ln1b, h, hb);

    // FFN1: W-resident relu->bf16, grid (2048/64, 16) = (32,16) = 512 blocks
    gemm_wres_k<<<dim3(32, 16), blk, 0, stream>>>(
        hb, W1b, b1, ff1b, nullptr, nullptr, nullptr,
        nullptr, nullptr, nullptr, DFF, DD, 3);

    // FFN2: W-resident split-K=4, grid (8,16,4) = 512 blocks
    gemm_wres_k<<<dim3(8, 16, 4), blk, 0, stream>>>(
        ff1b, W2b, nullptr, part, nullptr, nullptr, nullptr,
        nullptr, nullptr, nullptr, DD, DFF, 0);
    // LN2 fused reduce: 4 parts + b2 + h -> out
    ln_red_k<<<dim3(MM), blk, 0, stream>>>(
        part, 4, b2, h, ln2g, ln2b, out, nullptr);
}

// Round 14
// 232.410 us; speedup vs baseline: 1.1131x; 1.1131x over previous
//
#include <hip/hip_runtime.h>
#include <hip/hip_bf16.h>
#include <math.h>

// Problem constants (DecoderBlock: B=2, S=2048, D=512, H=8, DFF=2048)
#define BB 2
#define SS 2048
#define DD 512
#define HH 8
#define DH 64
#define DFF 2048
#define MM (BB*SS)          // 4096 rows
#define EPS 1e-5f

typedef __attribute__((ext_vector_type(8))) short bf16x8;
typedef __attribute__((ext_vector_type(4))) float f32x4;

// Async global->LDS, 16B per lane. LDS dest is wave-uniform base + lane*16;
// the GLOBAL address may be per-lane (gather) — only the LDS side is linear.
#define GL2LDS(g, l)                                                        \
    __builtin_amdgcn_global_load_lds(                                       \
        (const __attribute__((address_space(1))) void*)(unsigned long long)(g), \
        (__attribute__((address_space(3))) void*)(unsigned int)(unsigned long long)(l), \
        16, 0, 0)

// ---------------------------------------------------------------------------
// fp32 -> bf16 conversion for x + 6 weight matrices, one launch.
// ---------------------------------------------------------------------------
struct Cvt7 {
    const float* s[7];
    unsigned short* d[7];
    unsigned off[8];   // prefix offsets in float4 units
};

__global__ __launch_bounds__(256) void cvt_k(Cvt7 a)
{
    unsigned i = blockIdx.x * 256 + threadIdx.x;
    int seg = 0;
    #pragma unroll
    for (int t = 1; t < 7; ++t) seg += (i >= a.off[t]);
    unsigned li = i - a.off[seg];
    float4 v = ((const float4*)a.s[seg])[li];
    union { __hip_bfloat16 h[4]; uint2 u; } t;
    t.h[0] = __float2bfloat16(v.x);
    t.h[1] = __float2bfloat16(v.y);
    t.h[2] = __float2bfloat16(v.z);
    t.h[3] = __float2bfloat16(v.w);
    ((uint2*)a.d[seg])[li] = t.u;
}

// ---------------------------------------------------------------------------
// 64x64 bf16 MFMA GEMM (r12 structure + r14 rotation-swizzled LDS).
// Swizzle: LDS pos p of row r holds global k-chunk (p + r) & 7 (16B chunks);
// read chunk g of row r at pos (g - r) & 7. Kills the 16-way ds_read_b128
// bank conflict of the plain frag-order layout (bank was f(quad) only).
// mode: 0 fp32 [M,N]+resid | 3 bf16 [M,N] ReLU
// ---------------------------------------------------------------------------
__global__ __launch_bounds__(256) void gemm64_k(
    const __hip_bfloat16* __restrict__ A, const __hip_bfloat16* __restrict__ Bw,
    const float* __restrict__ bias, const float* __restrict__ resid,
    void* __restrict__ Cout, int N_, int K_, int mode, float oscale)
{
    __shared__ __hip_bfloat16 As[64*64];
    __shared__ __hip_bfloat16 Bs[64*64];
    const int tid   = threadIdx.x;
    const int w     = tid >> 6;
    const int lane  = tid & 63;
    const int quad  = lane >> 4;
    const int col16 = lane & 15;
    const int m0 = blockIdx.y * 64;
    const int n0 = blockIdx.x * 64;
    const int wm = (w >> 1) * 32;
    const int wn = (w & 1) * 32;
    const int srow = lane >> 3;
    const int scol = (((lane & 7) + srow) & 7) * 8;   // rotation-swizzled

    f32x4 acc[2][2] = {};

    for (int k0 = 0; k0 < K_; k0 += 64) {
        __syncthreads();
        #pragma unroll
        for (int t = 0; t < 4; ++t) {
            const int c = w * 4 + t;             // 16 chunks: 8 A + 8 B
            if (c < 8)
                GL2LDS(A  + (size_t)(m0 + c*8 + srow) * K_ + k0 + scol,
                       (char*)As + c * 1024);
            else
                GL2LDS(Bw + (size_t)(n0 + (c-8)*8 + srow) * K_ + k0 + scol,
                       (char*)Bs + (c-8) * 1024);
        }
        __syncthreads();

        #pragma unroll
        for (int kk = 0; kk < 64; kk += 32) {
            bf16x8 af[2], bf[2];
            #pragma unroll
            for (int i = 0; i < 2; ++i) {
                const int row = wm + i*16 + col16;
                af[i] = *(const bf16x8*)(As + row*64
                          + ((((kk>>3) + quad) - (row & 7)) & 7) * 8);
            }
            #pragma unroll
            for (int j = 0; j < 2; ++j) {
                const int row = wn + j*16 + col16;
                bf[j] = *(const bf16x8*)(Bs + row*64
                          + ((((kk>>3) + quad) - (row & 7)) & 7) * 8);
            }
            #pragma unroll
            for (int i = 0; i < 2; ++i)
                #pragma unroll
                for (int j = 0; j < 2; ++j)
                    acc[i][j] = __builtin_amdgcn_mfma_f32_16x16x32_bf16(
                        af[i], bf[j], acc[i][j], 0, 0, 0);
        }
    }

    #pragma unroll
    for (int i = 0; i < 2; ++i) {
        #pragma unroll
        for (int r = 0; r < 4; ++r) {
            const int m = m0 + wm + i*16 + quad*4 + r;
            #pragma unroll
            for (int j = 0; j < 2; ++j) {
                const int n = n0 + wn + j*16 + col16;
                float vv = acc[i][j][r] + bias[n];
                if (mode == 0) {
                    size_t idx = (size_t)m * N_ + n;
                    float* Cf = (float*)Cout;
                    if (resid) vv += resid[idx];
                    Cf[idx] = vv;
                } else {
                    ((__hip_bfloat16*)Cout)[(size_t)m * N_ + n] =
                        __float2bfloat16(fmaxf(vv, 0.f) * oscale);
                }
            }
        }
    }
}

// ---------------------------------------------------------------------------
// 64x64 split-K GEMM (r12 + swizzle): blockIdx.z selects K-segment.
// Raw fp32 partials (no bias) to part + z*M*N. Reduce fused into ln_red_k.
// ---------------------------------------------------------------------------
__global__ __launch_bounds__(256) void gemm64sk_k(
    const __hip_bfloat16* __restrict__ A, const __hip_bfloat16* __restrict__ Bw,
    float* __restrict__ part, int N_, int Ktot, int Kseg)
{
    __shared__ __hip_bfloat16 As[64*64];
    __shared__ __hip_bfloat16 Bs[64*64];
    const int tid   = threadIdx.x;
    const int w     = tid >> 6;
    const int lane  = tid & 63;
    const int quad  = lane >> 4;
    const int col16 = lane & 15;
    const int m0 = blockIdx.y * 64;
    const int n0 = blockIdx.x * 64;
    const int wm = (w >> 1) * 32;
    const int wn = (w & 1) * 32;
    const int srow = lane >> 3;
    const int scol = (((lane & 7) + srow) & 7) * 8;   // rotation-swizzled
    const int kbeg = blockIdx.z * Kseg;

    f32x4 acc[2][2] = {};

    for (int k0 = kbeg; k0 < kbeg + Kseg; k0 += 64) {
        __syncthreads();
        #pragma unroll
        for (int t = 0; t < 4; ++t) {
            const int c = w * 4 + t;
            if (c < 8)
                GL2LDS(A  + (size_t)(m0 + c*8 + srow) * Ktot + k0 + scol,
                       (char*)As + c * 1024);
            else
                GL2LDS(Bw + (size_t)(n0 + (c-8)*8 + srow) * Ktot + k0 + scol,
                       (char*)Bs + (c-8) * 1024);
        }
        __syncthreads();

        #pragma unroll
        for (int kk = 0; kk < 64; kk += 32) {
            bf16x8 af[2], bf[2];
            #pragma unroll
            for (int i = 0; i < 2; ++i) {
                const int row = wm + i*16 + col16;
                af[i] = *(const bf16x8*)(As + row*64
                          + ((((kk>>3) + quad) - (row & 7)) & 7) * 8);
            }
            #pragma unroll
            for (int j = 0; j < 2; ++j) {
                const int row = wn + j*16 + col16;
                bf[j] = *(const bf16x8*)(Bs + row*64
                          + ((((kk>>3) + quad) - (row & 7)) & 7) * 8);
            }
            #pragma unroll
            for (int i = 0; i < 2; ++i)
                #pragma unroll
                for (int j = 0; j < 2; ++j)
                    acc[i][j] = __builtin_amdgcn_mfma_f32_16x16x32_bf16(
                        af[i], bf[j], acc[i][j], 0, 0, 0);
        }
    }

    float* dst = part + (size_t)blockIdx.z * MM * N_;
    #pragma unroll
    for (int i = 0; i < 2; ++i)
        #pragma unroll
        for (int r = 0; r < 4; ++r) {
            const int m = m0 + wm + i*16 + quad*4 + r;
            #pragma unroll
            for (int j = 0; j < 2; ++j) {
                const int n = n0 + wn + j*16 + col16;
                dst[(size_t)m * N_ + n] = acc[i][j][r];
            }
        }
}

// ---------------------------------------------------------------------------
// Fused QKV GEMM, 64x64 tiles (r12 + swizzle): 1536 blocks (6/CU).
// Block-uniform z = n0>>9 selects bias/scale/output-layout.
// ---------------------------------------------------------------------------
__global__ __launch_bounds__(256) void qkv64_k(
    const __hip_bfloat16* __restrict__ A, const __hip_bfloat16* __restrict__ Wqkv,
    const float* __restrict__ bq, const float* __restrict__ bk,
    const float* __restrict__ bv,
    __hip_bfloat16* __restrict__ qb, __hip_bfloat16* __restrict__ kb,
    __hip_bfloat16* __restrict__ vtb)
{
    __shared__ __hip_bfloat16 As[64*64];
    __shared__ __hip_bfloat16 Bs[64*64];
    const int tid   = threadIdx.x;
    const int w     = tid >> 6;
    const int lane  = tid & 63;
    const int quad  = lane >> 4;
    const int col16 = lane & 15;
    const int m0 = blockIdx.y * 64;
    const int n0 = blockIdx.x * 64;
    const int wm = (w >> 1) * 32;
    const int wn = (w & 1) * 32;
    const int srow = lane >> 3;
    const int scol = (((lane & 7) + srow) & 7) * 8;   // rotation-swizzled

    f32x4 acc[2][2] = {};

    for (int k0 = 0; k0 < DD; k0 += 64) {
        __syncthreads();
        #pragma unroll
        for (int t = 0; t < 4; ++t) {
            const int c = w * 4 + t;
            if (c < 8)
                GL2LDS(A    + (size_t)(m0 + c*8 + srow) * DD + k0 + scol,
                       (char*)As + c * 1024);
            else
                GL2LDS(Wqkv + (size_t)(n0 + (c-8)*8 + srow) * DD + k0 + scol,
                       (char*)Bs + (c-8) * 1024);
        }
        __syncthreads();

        #pragma unroll
        for (int kk = 0; kk < 64; kk += 32) {
            bf16x8 af[2], bf[2];
            #pragma unroll
            for (int i = 0; i < 2; ++i) {
                const int row = wm + i*16 + col16;
                af[i] = *(const bf16x8*)(As + row*64
                          + ((((kk>>3) + quad) - (row & 7)) & 7) * 8);
            }
            #pragma unroll
            for (int j = 0; j < 2; ++j) {
                const int row = wn + j*16 + col16;
                bf[j] = *(const bf16x8*)(Bs + row*64
                          + ((((kk>>3) + quad) - (row & 7)) & 7) * 8);
            }
            #pragma unroll
            for (int i = 0; i < 2; ++i)
                #pragma unroll
                for (int j = 0; j < 2; ++j)
                    acc[i][j] = __builtin_amdgcn_mfma_f32_16x16x32_bf16(
                        af[i], bf[j], acc[i][j], 0, 0, 0);
        }
    }

    const int z = n0 >> 9;                       // uniform per block
    const float* bias = (z == 0) ? bq : (z == 1) ? bk : bv;
    __hip_bfloat16* dst = (z == 0) ? qb : (z == 1) ? kb : vtb;
    const float sc = (z == 0) ? 0.125f : 1.0f;
    #pragma unroll
    for (int i = 0; i < 2; ++i)
        #pragma unroll
        for (int r = 0; r < 4; ++r) {
            const int m = m0 + wm + i*16 + quad*4 + r;
            const int b = m >> 11, s = m & (SS - 1);
            #pragma unroll
            for (int j = 0; j < 2; ++j) {
                const int n  = n0 + wn + j*16 + col16;
                const int nn = n & 511;
                const int hh = nn >> 6, d = nn & (DH - 1);
                float vv = (acc[i][j][r] + bias[nn]) * sc;
                if (z < 2)
                    dst[(((size_t)(b*HH + hh))*SS + s)*DH + d] = __float2bfloat16(vv);
                else
                    dst[(((size_t)(b*HH + hh))*DH + d)*SS + s] = __float2bfloat16(vv);
            }
        }
}

// ---------------------------------------------------------------------------
// MFMA flash attention, causal — r11/r12's 8-wave version (unchanged).
// ---------------------------------------------------------------------------
__global__ __launch_bounds__(512) void attn_mfma_k(
    const __hip_bfloat16* __restrict__ Q,
    const __hip_bfloat16* __restrict__ K,
    const __hip_bfloat16* __restrict__ VT,
    const float* __restrict__ halpha,
    __hip_bfloat16* __restrict__ ctx)
{
    const int w    = threadIdx.x >> 6;   // 0..7
    const int lane = threadIdx.x & 63;
    const int quad = lane >> 4;
    const int col  = lane & 15;
    const int bh   = blockIdx.x;
    const int b    = bh >> 3, h = bh & 7;
    const int qt   = gridDim.y - 1 - blockIdx.y;   // deepest tiles first
    const int q0   = qt * 64;
    const int nchunk = qt + 1;

    const __hip_bfloat16* Qbh = Q  + (size_t)bh * SS * DH;
    const __hip_bfloat16* Kbh = K  + (size_t)bh * SS * DH;
    const __hip_bfloat16* Vbh = VT + (size_t)bh * DH * SS;

    __shared__ float smem[16896];
    __hip_bfloat16* bb     = (__hip_bfloat16*)smem;
    __hip_bfloat16* p_base = bb + (size_t)w * 4096;
    float* lbuf = smem + 16384;

    bf16x8 qf[4][2];
    #pragma unroll
    for (int mi = 0; mi < 4; ++mi) {
        const __hip_bfloat16* qp = Qbh + (size_t)(q0 + mi*16 + col) * DH + quad * 8;
        qf[mi][0] = *(const bf16x8*)(qp);
        qf[mi][1] = *(const bf16x8*)(qp + 32);
    }

    f32x4 acc_o[4][4] = {};
    float lp[4][4] = {};

    for (int c = w; c < nchunk; c += 8) {
        const int k0 = c * 64;
        const bool diag = (c == qt);

        #pragma unroll
        for (int ks = 0; ks < 4; ++ks) {
            const __hip_bfloat16* kp = Kbh + (size_t)(k0 + ks*16 + col) * DH + quad * 8;
            bf16x8 kb0 = *(const bf16x8*)(kp);
            bf16x8 kb1 = *(const bf16x8*)(kp + 32);
            const int keyl = ks*16 + col;
            const int kh = keyl >> 5;
            const int lr = ((keyl >> 3) & 3) * 16;
            const int j  = keyl & 7;
            const int kg = k0 + keyl;
            #pragma unroll
            for (int mi = 0; mi < 4; ++mi) {
                f32x4 s = {};
                s = __builtin_amdgcn_mfma_f32_16x16x32_bf16(qf[mi][0], kb0, s, 0, 0, 0);
                s = __builtin_amdgcn_mfma_f32_16x16x32_bf16(qf[mi][1], kb1, s, 0, 0, 0);
                #pragma unroll
                for (int r = 0; r < 4; ++r) {
                    float p;
                    if (diag) {
                        int qg = q0 + mi*16 + quad*4 + r;
                        p = (kg > qg) ? 0.f : __expf(s[r]);
                    } else {
                        p = __expf(s[r]);
                    }
                    lp[mi][r] += p;
                    p_base[mi*1024 + kh*512 + (lr + quad*4 + r)*8 + j] =
                        __float2bfloat16(p);
                }
            }
        }

        bf16x8 pa[4][2];
        #pragma unroll
        for (int mi = 0; mi < 4; ++mi) {
            pa[mi][0] = *(const bf16x8*)(p_base + mi*1024 + lane*8);
            pa[mi][1] = *(const bf16x8*)(p_base + mi*1024 + 512 + lane*8);
        }
        #pragma unroll
        for (int d = 0; d < 4; ++d) {
            const __hip_bfloat16* vp = Vbh + (size_t)(d*16 + col) * SS + k0 + quad * 8;
            bf16x8 vb0 = *(const bf16x8*)(vp);
            bf16x8 vb1 = *(const bf16x8*)(vp + 32);
            #pragma unroll
            for (int mi = 0; mi < 4; ++mi) {
                acc_o[mi][d] = __builtin_amdgcn_mfma_f32_16x16x32_bf16(pa[mi][0], vb0, acc_o[mi][d], 0, 0, 0);
                acc_o[mi][d] = __builtin_amdgcn_mfma_f32_16x16x32_bf16(pa[mi][1], vb1, acc_o[mi][d], 0, 0, 0);
            }
        }
    }

    #pragma unroll
    for (int mi = 0; mi < 4; ++mi)
        #pragma unroll
        for (int r = 0; r < 4; ++r) {
            float s_ = lp[mi][r];
            #pragma unroll
            for (int o = 1; o < 16; o <<= 1) s_ += __shfl_xor(s_, o);
            lp[mi][r] = s_;
        }

    __syncthreads();
    __hip_bfloat16* obuf = bb + (size_t)w * 4096;
    #pragma unroll
    for (int mi = 0; mi < 4; ++mi)
        #pragma unroll
        for (int d = 0; d < 4; ++d)
            #pragma unroll
            for (int r = 0; r < 4; ++r)
                obuf[(mi*16 + quad*4 + r)*64 + d*16 + col] =
                    __float2bfloat16(acc_o[mi][d][r]);
    if (col == 0) {
        #pragma unroll
        for (int mi = 0; mi < 4; ++mi)
            #pragma unroll
            for (int r = 0; r < 4; ++r)
                lbuf[w*64 + mi*16 + quad*4 + r] = lp[mi][r];
    }
    __syncthreads();

    const float ha = halpha[h];
    #pragma unroll
    for (int rr = 0; rr < 8; ++rr) {
        const int row = w*8 + rr;
        float L = 0.f, val = 0.f;
        #pragma unroll
        for (int p = 0; p < 8; ++p) {
            L   += lbuf[p*64 + row];
            val += __bfloat162float(bb[p*4096 + row*64 + lane]);
        }
        ctx[((size_t)(b*SS + q0 + row))*DD + h*64 + lane] =
            __float2bfloat16(val * ha / L);
    }
}

// ---------------------------------------------------------------------------
// Fused split-K reduce + bias + residual + LayerNorm (512 cols, 1 row/block).
// ---------------------------------------------------------------------------
__global__ __launch_bounds__(256) void ln_red_k(
    const float* __restrict__ pa, const float* __restrict__ pb,
    const float* __restrict__ bias, const float* __restrict__ resid,
    const float* __restrict__ g, const float* __restrict__ bta,
    float* __restrict__ out, __hip_bfloat16* __restrict__ outb)
{
    const int row = blockIdx.x;
    const size_t base = (size_t)row * DD;
    const int t = threadIdx.x;
    float v0 = pa[base + t]       + pb[base + t]       + bias[t]       + resid[base + t];
    float v1 = pa[base + t + 256] + pb[base + t + 256] + bias[t + 256] + resid[base + t + 256];
    __shared__ float red[256];
    red[t] = v0 + v1;
    __syncthreads();
    for (int o = 128; o > 0; o >>= 1) { if (t < o) red[t] += red[t + o]; __syncthreads(); }
    float mu = red[0] * (1.f / DD);
    __syncthreads();
    float d0 = v0 - mu, d1 = v1 - mu;
    red[t] = d0*d0 + d1*d1;
    __syncthreads();
    for (int o = 128; o > 0; o >>= 1) { if (t < o) red[t] += red[t + o]; __syncthreads(); }
    float rstd = rsqrtf(red[0] * (1.f / DD) + EPS);
    float o0 = d0 * rstd * g[t]       + bta[t];
    float o1 = d1 * rstd * g[t + 256] + bta[t + 256];
    out[base + t]       = o0;
    out[base + t + 256] = o1;
    if (outb) {
        outb[base + t]       = __float2bfloat16(o0);
        outb[base + t + 256] = __float2bfloat16(o1);
    }
}

// ---------------------------------------------------------------------------
extern "C" void kernel_launch(void* const* d_in, const int* in_sizes, int n_in,
                              void* d_out, int out_size, void* d_ws, size_t ws_size,
                              hipStream_t stream)
{
    const float* x    = (const float*)d_in[0];
    // d_in[1] = attn_mask (standard causal; handled structurally)
    const float* Wq   = (const float*)d_in[2];
    const float* bq   = (const float*)d_in[3];
    const float* Wk   = (const float*)d_in[4];
    const float* bk   = (const float*)d_in[5];
    const float* Wv   = (const float*)d_in[6];
    const float* bv   = (const float*)d_in[7];
    const float* Wo   = (const float*)d_in[8];
    const float* bo   = (const float*)d_in[9];
    const float* hal  = (const float*)d_in[10];
    const float* ln1g = (const float*)d_in[11];
    const float* ln1b = (const float*)d_in[12];
    const float* W1   = (const float*)d_in[13];
    const float* b1   = (const float*)d_in[14];
    const float* W2   = (const float*)d_in[15];
    const float* b2   = (const float*)d_in[16];
    const float* ln2g = (const float*)d_in[17];
    const float* ln2b = (const float*)d_in[18];
    float* out = (float*)d_out;

    char* ws = (char*)d_ws;
    const size_t MB = 1ull << 20;
    // Lifetime plan (peak 50 MiB) — identical to r12:
    __hip_bfloat16* Wqkv = (__hip_bfloat16*)(ws);
    __hip_bfloat16* Wob  = (__hip_bfloat16*)(ws + MB + MB/2);
    __hip_bfloat16* W1b  = (__hip_bfloat16*)(ws + 2*MB);
    __hip_bfloat16* W2b  = (__hip_bfloat16*)(ws + 4*MB);
    __hip_bfloat16* xb   = (__hip_bfloat16*)(ws + 6*MB);
    __hip_bfloat16* qb   = (__hip_bfloat16*)(ws + 10*MB);
    __hip_bfloat16* kb   = (__hip_bfloat16*)(ws + 14*MB);
    __hip_bfloat16* vtb  = (__hip_bfloat16*)(ws + 18*MB);
    __hip_bfloat16* ctxb = (__hip_bfloat16*)(ws + 22*MB);
    float* part = (float*)(ws + 26*MB);           // 2 x 8 MiB segments
    float* h    = (float*)(ws + 42*MB);
    __hip_bfloat16* hb   = (__hip_bfloat16*)(ws + 22*MB);
    __hip_bfloat16* ff1b = (__hip_bfloat16*)(ws + 6*MB);

    dim3 blk(256);
    const size_t PSEG = (size_t)MM * DD;          // floats per partial

    // fp32 -> bf16: x, Wq, Wk, Wv, Wo, W1, W2 (Wq/Wk/Wv contiguous -> Wqkv)
    Cvt7 ca;
    ca.s[0] = x;  ca.d[0] = (unsigned short*)xb;
    ca.s[1] = Wq; ca.d[1] = (unsigned short*)Wqkv;
    ca.s[2] = Wk; ca.d[2] = (unsigned short*)(Wqkv + 512*512);
    ca.s[3] = Wv; ca.d[3] = (unsigned short*)(Wqkv + 2*512*512);
    ca.s[4] = Wo; ca.d[4] = (unsigned short*)Wob;
    ca.s[5] = W1; ca.d[5] = (unsigned short*)W1b;
    ca.s[6] = W2; ca.d[6] = (unsigned short*)W2b;
    unsigned offs[8] = {0, 524288, 589824, 655360, 720896, 786432, 1048576, 1310720};
    for (int i = 0; i < 8; ++i) ca.off[i] = offs[i];
    cvt_k<<<dim3(5120), blk, 0, stream>>>(ca);

    // QKV: 64x64 tiles over N=1536 -> (24,64) = 1536 blocks (6/CU)
    qkv64_k<<<dim3((3*DD)/64, MM/64), blk, 0, stream>>>(
        xb, Wqkv, bq, bk, bv, qb, kb, vtb);

    // MFMA flash attention (64q tiles, 8-wave blocks, chunks mod 8)
    attn_mfma_k<<<dim3(BB*HH, SS/64), dim3(512), 0, stream>>>(
        qb, kb, vtb, hal, ctxb);

    // Out-proj: split-K=2 (Kseg=256), (8,64,2) = 1024 blocks (4/CU)
    gemm64sk_k<<<dim3(DD/64, MM/64, 2), blk, 0, stream>>>(
        ctxb, Wob, part, DD, DD, 256);
    // LN1 fused reduce: part0+part1+bo+x -> h, hb
    ln_red_k<<<dim3(MM), blk, 0, stream>>>(
        part, part + PSEG, bo, x, ln1g, ln1b, h, hb);

    // FFN1: relu -> bf16 [M,DFF], 64x64 tiles (32,64) = 2048 blocks (8/CU)
    gemm64_k<<<dim3(DFF/64, MM/64), blk, 0, stream>>>(
        hb, W1b, b1, nullptr, ff1b, DFF, DD, 3, 1.0f);

    // FFN2: split-K=2 (Kseg=1024), (8,64,2) = 1024 blocks (4/CU)
    gemm64sk_k<<<dim3(DD/64, MM/64, 2), blk, 0, stream>>>(
        ff1b, W2b, part, DD, DFF, 1024);
    // LN2 fused reduce: part0+part1+b2+h -> out
    ln_red_k<<<dim3(MM), blk, 0, stream>>>(
        part, part + PSEG, b2, h, ln2g, ln2b, out, nullptr);
}

// Round 15
// 230.937 us; speedup vs baseline: 1.1202x; 1.0064x over previous
//
#include <hip/hip_runtime.h>
#include <hip/hip_bf16.h>
#include <math.h>

// Problem constants (DecoderBlock: B=2, S=2048, D=512, H=8, DFF=2048)
#define BB 2
#define SS 2048
#define DD 512
#define HH 8
#define DH 64
#define DFF 2048
#define MM (BB*SS)          // 4096 rows
#define EPS 1e-5f

typedef __attribute__((ext_vector_type(8))) short bf16x8;
typedef __attribute__((ext_vector_type(4))) float f32x4;

// Async global->LDS, 16B per lane. LDS dest is wave-uniform base + lane*16;
// the GLOBAL address may be per-lane (gather) — only the LDS side is linear.
#define GL2LDS(g, l)                                                        \
    __builtin_amdgcn_global_load_lds(                                       \
        (const __attribute__((address_space(1))) void*)(unsigned long long)(g), \
        (__attribute__((address_space(3))) void*)(unsigned int)(unsigned long long)(l), \
        16, 0, 0)

// ---------------------------------------------------------------------------
// fp32 -> bf16 conversion for x + 6 weight matrices, one launch.
// ---------------------------------------------------------------------------
struct Cvt7 {
    const float* s[7];
    unsigned short* d[7];
    unsigned off[8];   // prefix offsets in float4 units
};

__global__ __launch_bounds__(256) void cvt_k(Cvt7 a)
{
    unsigned i = blockIdx.x * 256 + threadIdx.x;
    int seg = 0;
    #pragma unroll
    for (int t = 1; t < 7; ++t) seg += (i >= a.off[t]);
    unsigned li = i - a.off[seg];
    float4 v = ((const float4*)a.s[seg])[li];
    union { __hip_bfloat16 h[4]; uint2 u; } t;
    t.h[0] = __float2bfloat16(v.x);
    t.h[1] = __float2bfloat16(v.y);
    t.h[2] = __float2bfloat16(v.z);
    t.h[3] = __float2bfloat16(v.w);
    ((uint2*)a.d[seg])[li] = t.u;
}

// ---------------------------------------------------------------------------
// 64x64 bf16 MFMA GEMM (r12 structure + r14 rotation-swizzled LDS).
// mode: 0 fp32 [M,N]+resid | 3 bf16 [M,N] ReLU
// ---------------------------------------------------------------------------
__global__ __launch_bounds__(256) void gemm64_k(
    const __hip_bfloat16* __restrict__ A, const __hip_bfloat16* __restrict__ Bw,
    const float* __restrict__ bias, const float* __restrict__ resid,
    void* __restrict__ Cout, int N_, int K_, int mode, float oscale)
{
    __shared__ __hip_bfloat16 As[64*64];
    __shared__ __hip_bfloat16 Bs[64*64];
    const int tid   = threadIdx.x;
    const int w     = tid >> 6;
    const int lane  = tid & 63;
    const int quad  = lane >> 4;
    const int col16 = lane & 15;
    const int m0 = blockIdx.y * 64;
    const int n0 = blockIdx.x * 64;
    const int wm = (w >> 1) * 32;
    const int wn = (w & 1) * 32;
    const int srow = lane >> 3;
    const int scol = (((lane & 7) + srow) & 7) * 8;   // rotation-swizzled

    f32x4 acc[2][2] = {};

    for (int k0 = 0; k0 < K_; k0 += 64) {
        __syncthreads();
        #pragma unroll
        for (int t = 0; t < 4; ++t) {
            const int c = w * 4 + t;             // 16 chunks: 8 A + 8 B
            if (c < 8)
                GL2LDS(A  + (size_t)(m0 + c*8 + srow) * K_ + k0 + scol,
                       (char*)As + c * 1024);
            else
                GL2LDS(Bw + (size_t)(n0 + (c-8)*8 + srow) * K_ + k0 + scol,
                       (char*)Bs + (c-8) * 1024);
        }
        __syncthreads();

        #pragma unroll
        for (int kk = 0; kk < 64; kk += 32) {
            bf16x8 af[2], bf[2];
            #pragma unroll
            for (int i = 0; i < 2; ++i) {
                const int row = wm + i*16 + col16;
                af[i] = *(const bf16x8*)(As + row*64
                          + ((((kk>>3) + quad) - (row & 7)) & 7) * 8);
            }
            #pragma unroll
            for (int j = 0; j < 2; ++j) {
                const int row = wn + j*16 + col16;
                bf[j] = *(const bf16x8*)(Bs + row*64
                          + ((((kk>>3) + quad) - (row & 7)) & 7) * 8);
            }
            #pragma unroll
            for (int i = 0; i < 2; ++i)
                #pragma unroll
                for (int j = 0; j < 2; ++j)
                    acc[i][j] = __builtin_amdgcn_mfma_f32_16x16x32_bf16(
                        af[i], bf[j], acc[i][j], 0, 0, 0);
        }
    }

    #pragma unroll
    for (int i = 0; i < 2; ++i) {
        #pragma unroll
        for (int r = 0; r < 4; ++r) {
            const int m = m0 + wm + i*16 + quad*4 + r;
            #pragma unroll
            for (int j = 0; j < 2; ++j) {
                const int n = n0 + wn + j*16 + col16;
                float vv = acc[i][j][r] + bias[n];
                if (mode == 0) {
                    size_t idx = (size_t)m * N_ + n;
                    float* Cf = (float*)Cout;
                    if (resid) vv += resid[idx];
                    Cf[idx] = vv;
                } else {
                    ((__hip_bfloat16*)Cout)[(size_t)m * N_ + n] =
                        __float2bfloat16(fmaxf(vv, 0.f) * oscale);
                }
            }
        }
    }
}

// ---------------------------------------------------------------------------
// 64x64 split-K GEMM (r12 + swizzle): blockIdx.z selects K-segment.
// ---------------------------------------------------------------------------
__global__ __launch_bounds__(256) void gemm64sk_k(
    const __hip_bfloat16* __restrict__ A, const __hip_bfloat16* __restrict__ Bw,
    float* __restrict__ part, int N_, int Ktot, int Kseg)
{
    __shared__ __hip_bfloat16 As[64*64];
    __shared__ __hip_bfloat16 Bs[64*64];
    const int tid   = threadIdx.x;
    const int w     = tid >> 6;
    const int lane  = tid & 63;
    const int quad  = lane >> 4;
    const int col16 = lane & 15;
    const int m0 = blockIdx.y * 64;
    const int n0 = blockIdx.x * 64;
    const int wm = (w >> 1) * 32;
    const int wn = (w & 1) * 32;
    const int srow = lane >> 3;
    const int scol = (((lane & 7) + srow) & 7) * 8;   // rotation-swizzled
    const int kbeg = blockIdx.z * Kseg;

    f32x4 acc[2][2] = {};

    for (int k0 = kbeg; k0 < kbeg + Kseg; k0 += 64) {
        __syncthreads();
        #pragma unroll
        for (int t = 0; t < 4; ++t) {
            const int c = w * 4 + t;
            if (c < 8)
                GL2LDS(A  + (size_t)(m0 + c*8 + srow) * Ktot + k0 + scol,
                       (char*)As + c * 1024);
            else
                GL2LDS(Bw + (size_t)(n0 + (c-8)*8 + srow) * Ktot + k0 + scol,
                       (char*)Bs + (c-8) * 1024);
        }
        __syncthreads();

        #pragma unroll
        for (int kk = 0; kk < 64; kk += 32) {
            bf16x8 af[2], bf[2];
            #pragma unroll
            for (int i = 0; i < 2; ++i) {
                const int row = wm + i*16 + col16;
                af[i] = *(const bf16x8*)(As + row*64
                          + ((((kk>>3) + quad) - (row & 7)) & 7) * 8);
            }
            #pragma unroll
            for (int j = 0; j < 2; ++j) {
                const int row = wn + j*16 + col16;
                bf[j] = *(const bf16x8*)(Bs + row*64
                          + ((((kk>>3) + quad) - (row & 7)) & 7) * 8);
            }
            #pragma unroll
            for (int i = 0; i < 2; ++i)
                #pragma unroll
                for (int j = 0; j < 2; ++j)
                    acc[i][j] = __builtin_amdgcn_mfma_f32_16x16x32_bf16(
                        af[i], bf[j], acc[i][j], 0, 0, 0);
        }
    }

    float* dst = part + (size_t)blockIdx.z * MM * N_;
    #pragma unroll
    for (int i = 0; i < 2; ++i)
        #pragma unroll
        for (int r = 0; r < 4; ++r) {
            const int m = m0 + wm + i*16 + quad*4 + r;
            #pragma unroll
            for (int j = 0; j < 2; ++j) {
                const int n = n0 + wn + j*16 + col16;
                dst[(size_t)m * N_ + n] = acc[i][j][r];
            }
        }
}

// ---------------------------------------------------------------------------
// Fused QKV GEMM, 64x64 tiles (r12 + swizzle): 1536 blocks (6/CU).
// ---------------------------------------------------------------------------
__global__ __launch_bounds__(256) void qkv64_k(
    const __hip_bfloat16* __restrict__ A, const __hip_bfloat16* __restrict__ Wqkv,
    const float* __restrict__ bq, const float* __restrict__ bk,
    const float* __restrict__ bv,
    __hip_bfloat16* __restrict__ qb, __hip_bfloat16* __restrict__ kb,
    __hip_bfloat16* __restrict__ vtb)
{
    __shared__ __hip_bfloat16 As[64*64];
    __shared__ __hip_bfloat16 Bs[64*64];
    const int tid   = threadIdx.x;
    const int w     = tid >> 6;
    const int lane  = tid & 63;
    const int quad  = lane >> 4;
    const int col16 = lane & 15;
    const int m0 = blockIdx.y * 64;
    const int n0 = blockIdx.x * 64;
    const int wm = (w >> 1) * 32;
    const int wn = (w & 1) * 32;
    const int srow = lane >> 3;
    const int scol = (((lane & 7) + srow) & 7) * 8;   // rotation-swizzled

    f32x4 acc[2][2] = {};

    for (int k0 = 0; k0 < DD; k0 += 64) {
        __syncthreads();
        #pragma unroll
        for (int t = 0; t < 4; ++t) {
            const int c = w * 4 + t;
            if (c < 8)
                GL2LDS(A    + (size_t)(m0 + c*8 + srow) * DD + k0 + scol,
                       (char*)As + c * 1024);
            else
                GL2LDS(Wqkv + (size_t)(n0 + (c-8)*8 + srow) * DD + k0 + scol,
                       (char*)Bs + (c-8) * 1024);
        }
        __syncthreads();

        #pragma unroll
        for (int kk = 0; kk < 64; kk += 32) {
            bf16x8 af[2], bf[2];
            #pragma unroll
            for (int i = 0; i < 2; ++i) {
                const int row = wm + i*16 + col16;
                af[i] = *(const bf16x8*)(As + row*64
                          + ((((kk>>3) + quad) - (row & 7)) & 7) * 8);
            }
            #pragma unroll
            for (int j = 0; j < 2; ++j) {
                const int row = wn + j*16 + col16;
                bf[j] = *(const bf16x8*)(Bs + row*64
                          + ((((kk>>3) + quad) - (row & 7)) & 7) * 8);
            }
            #pragma unroll
            for (int i = 0; i < 2; ++i)
                #pragma unroll
                for (int j = 0; j < 2; ++j)
                    acc[i][j] = __builtin_amdgcn_mfma_f32_16x16x32_bf16(
                        af[i], bf[j], acc[i][j], 0, 0, 0);
        }
    }

    const int z = n0 >> 9;                       // uniform per block
    const float* bias = (z == 0) ? bq : (z == 1) ? bk : bv;
    __hip_bfloat16* dst = (z == 0) ? qb : (z == 1) ? kb : vtb;
    const float sc = (z == 0) ? 0.125f : 1.0f;
    #pragma unroll
    for (int i = 0; i < 2; ++i)
        #pragma unroll
        for (int r = 0; r < 4; ++r) {
            const int m = m0 + wm + i*16 + quad*4 + r;
            const int b = m >> 11, s = m & (SS - 1);
            #pragma unroll
            for (int j = 0; j < 2; ++j) {
                const int n  = n0 + wn + j*16 + col16;
                const int nn = n & 511;
                const int hh = nn >> 6, d = nn & (DH - 1);
                float vv = (acc[i][j][r] + bias[nn]) * sc;
                if (z < 2)
                    dst[(((size_t)(b*HH + hh))*SS + s)*DH + d] = __float2bfloat16(vv);
                else
                    dst[(((size_t)(b*HH + hh))*DH + d)*SS + s] = __float2bfloat16(vv);
            }
        }
}

// ---------------------------------------------------------------------------
// MFMA flash attention, causal — round 15: S-TRANSPOSED QK^T.
// mfma(K_frag, Q_frag) gives S^T (rows=keys, cols=queries) with the SAME
// loads as before (both K and Q memory layouts serve either operand). In
// S^T C-layout a lane's 4 regs are P[q=col][key=ks*16+quad*4+r] — 4
// consecutive keys — which in the (unchanged) A-operand P-buffer layout
// land at 4 consecutive bf16 = one aligned ds_write_b64. Per chunk-wave:
// 16 packed writes instead of r14's 64 scalar ds_write_b16 (which were the
// 1.6e6 SQ_LDS_BANK_CONFLICT + VALU serial tax). PV reads, merge, grids
// unchanged.
// ---------------------------------------------------------------------------
__global__ __launch_bounds__(512) void attn_mfma_k(
    const __hip_bfloat16* __restrict__ Q,
    const __hip_bfloat16* __restrict__ K,
    const __hip_bfloat16* __restrict__ VT,
    const float* __restrict__ halpha,
    __hip_bfloat16* __restrict__ ctx)
{
    const int w    = threadIdx.x >> 6;   // 0..7
    const int lane = threadIdx.x & 63;
    const int quad = lane >> 4;
    const int col  = lane & 15;
    const int bh   = blockIdx.x;
    const int b    = bh >> 3, h = bh & 7;
    const int qt   = gridDim.y - 1 - blockIdx.y;   // deepest tiles first
    const int q0   = qt * 64;
    const int nchunk = qt + 1;

    const __hip_bfloat16* Qbh = Q  + (size_t)bh * SS * DH;
    const __hip_bfloat16* Kbh = K  + (size_t)bh * SS * DH;
    const __hip_bfloat16* Vbh = VT + (size_t)bh * DH * SS;

    __shared__ float smem[16896];
    __hip_bfloat16* bb     = (__hip_bfloat16*)smem;
    __hip_bfloat16* p_base = bb + (size_t)w * 4096;
    float* lbuf = smem + 16384;

    bf16x8 qf[4][2];
    #pragma unroll
    for (int mi = 0; mi < 4; ++mi) {
        const __hip_bfloat16* qp = Qbh + (size_t)(q0 + mi*16 + col) * DH + quad * 8;
        qf[mi][0] = *(const bf16x8*)(qp);
        qf[mi][1] = *(const bf16x8*)(qp + 32);
    }

    f32x4 acc_o[4][4] = {};
    float lp[4] = {};                 // per-lane l partial (q = col), per mi

    for (int c = w; c < nchunk; c += 8) {
        const int k0 = c * 64;
        const bool diag = (c == qt);

        // ---- per-ks: S^T = K Q^T (16key x 16q per mi), exp, packed store ----
        #pragma unroll
        for (int ks = 0; ks < 4; ++ks) {
            const __hip_bfloat16* kp = Kbh + (size_t)(k0 + ks*16 + col) * DH + quad * 8;
            bf16x8 kb0 = *(const bf16x8*)(kp);
            bf16x8 kb1 = *(const bf16x8*)(kp + 32);
            const int kc = ks*2 + (quad >> 1);       // 8-key chunk index
            const int jb = (quad & 1) * 4;           // j base within chunk
            const int kgb = k0 + ks*16 + quad*4;     // this lane's first key
            #pragma unroll
            for (int mi = 0; mi < 4; ++mi) {
                f32x4 s = {};
                s = __builtin_amdgcn_mfma_f32_16x16x32_bf16(kb0, qf[mi][0], s, 0, 0, 0);
                s = __builtin_amdgcn_mfma_f32_16x16x32_bf16(kb1, qf[mi][1], s, 0, 0, 0);
                union { unsigned long long u; __hip_bfloat16 hh[4]; } pk;
                const int qg = q0 + mi*16 + col;
                float psum = 0.f;
                #pragma unroll
                for (int r = 0; r < 4; ++r) {
                    float p;
                    if (diag) p = (kgb + r > qg) ? 0.f : __expf(s[r]);
                    else      p = __expf(s[r]);
                    psum += p;
                    pk.hh[r] = __float2bfloat16(p);
                }
                lp[mi] += psum;
                *(unsigned long long*)(p_base + mi*1024 + kc*128 + col*8 + jb) = pk.u;
            }
        }

        // ---- O += P V (4 m-tiles x 4 d-tiles) ----
        bf16x8 pa[4][2];
        #pragma unroll
        for (int mi = 0; mi < 4; ++mi) {
            pa[mi][0] = *(const bf16x8*)(p_base + mi*1024 + lane*8);
            pa[mi][1] = *(const bf16x8*)(p_base + mi*1024 + 512 + lane*8);
        }
        #pragma unroll
        for (int d = 0; d < 4; ++d) {
            const __hip_bfloat16* vp = Vbh + (size_t)(d*16 + col) * SS + k0 + quad * 8;
            bf16x8 vb0 = *(const bf16x8*)(vp);
            bf16x8 vb1 = *(const bf16x8*)(vp + 32);
            #pragma unroll
            for (int mi = 0; mi < 4; ++mi) {
                acc_o[mi][d] = __builtin_amdgcn_mfma_f32_16x16x32_bf16(pa[mi][0], vb0, acc_o[mi][d], 0, 0, 0);
                acc_o[mi][d] = __builtin_amdgcn_mfma_f32_16x16x32_bf16(pa[mi][1], vb1, acc_o[mi][d], 0, 0, 0);
            }
        }
    }

    // ---- reduce l across the 4 key-quads (same q lives in 4 lanes) ----
    #pragma unroll
    for (int mi = 0; mi < 4; ++mi) {
        lp[mi] += __shfl_xor(lp[mi], 16);
        lp[mi] += __shfl_xor(lp[mi], 32);
    }

    // ---- phase switch: publish bf16 O partials + l ----
    __syncthreads();
    __hip_bfloat16* obuf = bb + (size_t)w * 4096;
    #pragma unroll
    for (int mi = 0; mi < 4; ++mi)
        #pragma unroll
        for (int d = 0; d < 4; ++d)
            #pragma unroll
            for (int r = 0; r < 4; ++r)
                obuf[(mi*16 + quad*4 + r)*64 + d*16 + col] =
                    __float2bfloat16(acc_o[mi][d][r]);
    if (quad == 0) {
        #pragma unroll
        for (int mi = 0; mi < 4; ++mi)
            lbuf[w*64 + mi*16 + col] = lp[mi];
    }
    __syncthreads();

    // ---- merge + write: wave w handles query rows w*8 .. w*8+7 ----
    const float ha = halpha[h];
    #pragma unroll
    for (int rr = 0; rr < 8; ++rr) {
        const int row = w*8 + rr;
        float L = 0.f, val = 0.f;
        #pragma unroll
        for (int p = 0; p < 8; ++p) {
            L   += lbuf[p*64 + row];
            val += __bfloat162float(bb[p*4096 + row*64 + lane]);
        }
        ctx[((size_t)(b*SS + q0 + row))*DD + h*64 + lane] =
            __float2bfloat16(val * ha / L);
    }
}

// ---------------------------------------------------------------------------
// Fused split-K reduce + bias + residual + LayerNorm (512 cols, 1 row/block).
// ---------------------------------------------------------------------------
__global__ __launch_bounds__(256) void ln_red_k(
    const float* __restrict__ pa, const float* __restrict__ pb,
    const float* __restrict__ bias, const float* __restrict__ resid,
    const float* __restrict__ g, const float* __restrict__ bta,
    float* __restrict__ out, __hip_bfloat16* __restrict__ outb)
{
    const int row = blockIdx.x;
    const size_t base = (size_t)row * DD;
    const int t = threadIdx.x;
    float v0 = pa[base + t]       + pb[base + t]       + bias[t]       + resid[base + t];
    float v1 = pa[base + t + 256] + pb[base + t + 256] + bias[t + 256] + resid[base + t + 256];
    __shared__ float red[256];
    red[t] = v0 + v1;
    __syncthreads();
    for (int o = 128; o > 0; o >>= 1) { if (t < o) red[t] += red[t + o]; __syncthreads(); }
    float mu = red[0] * (1.f / DD);
    __syncthreads();
    float d0 = v0 - mu, d1 = v1 - mu;
    red[t] = d0*d0 + d1*d1;
    __syncthreads();
    for (int o = 128; o > 0; o >>= 1) { if (t < o) red[t] += red[t + o]; __syncthreads(); }
    float rstd = rsqrtf(red[0] * (1.f / DD) + EPS);
    float o0 = d0 * rstd * g[t]       + bta[t];
    float o1 = d1 * rstd * g[t + 256] + bta[t + 256];
    out[base + t]       = o0;
    out[base + t + 256] = o1;
    if (outb) {
        outb[base + t]       = __float2bfloat16(o0);
        outb[base + t + 256] = __float2bfloat16(o1);
    }
}

// ---------------------------------------------------------------------------
extern "C" void kernel_launch(void* const* d_in, const int* in_sizes, int n_in,
                              void* d_out, int out_size, void* d_ws, size_t ws_size,
                              hipStream_t stream)
{
    const float* x    = (const float*)d_in[0];
    // d_in[1] = attn_mask (standard causal; handled structurally)
    const float* Wq   = (const float*)d_in[2];
    const float* bq   = (const float*)d_in[3];
    const float* Wk   = (const float*)d_in[4];
    const float* bk   = (const float*)d_in[5];
    const float* Wv   = (const float*)d_in[6];
    const float* bv   = (const float*)d_in[7];
    const float* Wo   = (const float*)d_in[8];
    const float* bo   = (const float*)d_in[9];
    const float* hal  = (const float*)d_in[10];
    const float* ln1g = (const float*)d_in[11];
    const float* ln1b = (const float*)d_in[12];
    const float* W1   = (const float*)d_in[13];
    const float* b1   = (const float*)d_in[14];
    const float* W2   = (const float*)d_in[15];
    const float* b2   = (const float*)d_in[16];
    const float* ln2g = (const float*)d_in[17];
    const float* ln2b = (const float*)d_in[18];
    float* out = (float*)d_out;

    char* ws = (char*)d_ws;
    const size_t MB = 1ull << 20;
    // Lifetime plan (peak 50 MiB) — identical to r12/r14:
    __hip_bfloat16* Wqkv = (__hip_bfloat16*)(ws);
    __hip_bfloat16* Wob  = (__hip_bfloat16*)(ws + MB + MB/2);
    __hip_bfloat16* W1b  = (__hip_bfloat16*)(ws + 2*MB);
    __hip_bfloat16* W2b  = (__hip_bfloat16*)(ws + 4*MB);
    __hip_bfloat16* xb   = (__hip_bfloat16*)(ws + 6*MB);
    __hip_bfloat16* qb   = (__hip_bfloat16*)(ws + 10*MB);
    __hip_bfloat16* kb   = (__hip_bfloat16*)(ws + 14*MB);
    __hip_bfloat16* vtb  = (__hip_bfloat16*)(ws + 18*MB);
    __hip_bfloat16* ctxb = (__hip_bfloat16*)(ws + 22*MB);
    float* part = (float*)(ws + 26*MB);           // 2 x 8 MiB segments
    float* h    = (float*)(ws + 42*MB);
    __hip_bfloat16* hb   = (__hip_bfloat16*)(ws + 22*MB);
    __hip_bfloat16* ff1b = (__hip_bfloat16*)(ws + 6*MB);

    dim3 blk(256);
    const size_t PSEG = (size_t)MM * DD;          // floats per partial

    // fp32 -> bf16: x, Wq, Wk, Wv, Wo, W1, W2 (Wq/Wk/Wv contiguous -> Wqkv)
    Cvt7 ca;
    ca.s[0] = x;  ca.d[0] = (unsigned short*)xb;
    ca.s[1] = Wq; ca.d[1] = (unsigned short*)Wqkv;
    ca.s[2] = Wk; ca.d[2] = (unsigned short*)(Wqkv + 512*512);
    ca.s[3] = Wv; ca.d[3] = (unsigned short*)(Wqkv + 2*512*512);
    ca.s[4] = Wo; ca.d[4] = (unsigned short*)Wob;
    ca.s[5] = W1; ca.d[5] = (unsigned short*)W1b;
    ca.s[6] = W2; ca.d[6] = (unsigned short*)W2b;
    unsigned offs[8] = {0, 524288, 589824, 655360, 720896, 786432, 1048576, 1310720};
    for (int i = 0; i < 8; ++i) ca.off[i] = offs[i];
    cvt_k<<<dim3(5120), blk, 0, stream>>>(ca);

    // QKV: 64x64 tiles over N=1536 -> (24,64) = 1536 blocks (6/CU)
    qkv64_k<<<dim3((3*DD)/64, MM/64), blk, 0, stream>>>(
        xb, Wqkv, bq, bk, bv, qb, kb, vtb);

    // MFMA flash attention (64q tiles, 8-wave blocks, S^T transpose)
    attn_mfma_k<<<dim3(BB*HH, SS/64), dim3(512), 0, stream>>>(
        qb, kb, vtb, hal, ctxb);

    // Out-proj: split-K=2 (Kseg=256), (8,64,2) = 1024 blocks (4/CU)
    gemm64sk_k<<<dim3(DD/64, MM/64, 2), blk, 0, stream>>>(
        ctxb, Wob, part, DD, DD, 256);
    // LN1 fused reduce: part0+part1+bo+x -> h, hb
    ln_red_k<<<dim3(MM), blk, 0, stream>>>(
        part, part + PSEG, bo, x, ln1g, ln1b, h, hb);

    // FFN1: relu -> bf16 [M,DFF], 64x64 tiles (32,64) = 2048 blocks (8/CU)
    gemm64_k<<<dim3(DFF/64, MM/64), blk, 0, stream>>>(
        hb, W1b, b1, nullptr, ff1b, DFF, DD, 3, 1.0f);

    // FFN2: split-K=2 (Kseg=1024), (8,64,2) = 1024 blocks (4/CU)
    gemm64sk_k<<<dim3(DD/64, MM/64, 2), blk, 0, stream>>>(
        ff1b, W2b, part, DD, DFF, 1024);
    // LN2 fused reduce: part0+part1+b2+h -> out
    ln_red_k<<<dim3(MM), blk, 0, stream>>>(
        part, part + PSEG, b2, h, ln2g, ln2b, out, nullptr);
}